// Round 2
// baseline (930.679 us; speedup 1.0000x reference)
//
#include <hip/hip_runtime.h>
#include <hip/hip_bf16.h>
#include <math.h>

// ---------------------------------------------------------------------------
// GAT 2-layer decoder. N=50000 nodes, E=800000 edges, DIN=128.
// Layer1: W1[128,128], H=2, D=64, elu. Layer2: W2[128,256], H=4, D=64, relu.
// Output: mean over 4 heads -> [N,64] f32.
// Strategy: dst-CSR build (no float atomics), wave-per-node edge softmax +
// aggregation, f32 LDS-tiled GEMM (no fp32 MFMA on CDNA4).
// ---------------------------------------------------------------------------

#define DIN 128

__global__ void zero_i32(int* __restrict__ p, int n) {
    int i = blockIdx.x * 256 + threadIdx.x;
    if (i < n) p[i] = 0;
}

__global__ void count_deg(const int* __restrict__ dst, int* __restrict__ deg, int E) {
    int e = blockIdx.x * 256 + threadIdx.x;
    if (e < E) atomicAdd(&deg[dst[e]], 1);
}

// Single-block scan over deg -> row_ptr (exclusive), cursor copy, row_ptr[N]=E.
__global__ __launch_bounds__(1024) void scan_kernel(const int* __restrict__ deg,
                                                    int* __restrict__ row_ptr,
                                                    int* __restrict__ cursor, int N) {
    __shared__ int sums[1024];
    int t = threadIdx.x;
    int chunk = (N + 1023) / 1024;
    int b = t * chunk;
    int e = min(b + chunk, N);
    int s = 0;
    for (int i = b; i < e; ++i) s += deg[i];
    sums[t] = s;
    __syncthreads();
    // Hillis-Steele inclusive scan
    for (int o = 1; o < 1024; o <<= 1) {
        int v = (t >= o) ? sums[t - o] : 0;
        __syncthreads();
        sums[t] += v;
        __syncthreads();
    }
    int run = (t == 0) ? 0 : sums[t - 1];
    for (int i = b; i < e; ++i) {
        row_ptr[i] = run;
        cursor[i] = run;
        run += deg[i];
    }
    if (t == 0) row_ptr[N] = sums[1023];
}

__global__ void scatter_kernel(const int* __restrict__ src, const int* __restrict__ dst,
                               int* __restrict__ cursor, int* __restrict__ csr_src, int E) {
    int e = blockIdx.x * 256 + threadIdx.x;
    if (e < E) {
        int pos = atomicAdd(&cursor[dst[e]], 1);
        csr_src[pos] = src[e];
    }
}

// Y[N,M] = X[N,128] @ W[128,M].  BM=64, BN=64, BK=128(full K). 256 threads,
// each computes 4x4 outputs. grid = (ceil(N/64), M/64).
__global__ __launch_bounds__(256) void gemm_f32(const float* __restrict__ X,
                                                const float* __restrict__ W,
                                                float* __restrict__ Y, int N, int M) {
    __shared__ float xs[64][DIN + 1];  // stride 129: A-reads 2-way bank alias (free)
    __shared__ float wsm[DIN][64];
    int row0 = blockIdx.x * 64;
    int col0 = blockIdx.y * 64;
    int t = threadIdx.x;

    // stage X tile: 64 rows x 128 cols = 2048 float4, 8 per thread
    #pragma unroll
    for (int i = 0; i < 8; ++i) {
        int flat = t + i * 256;
        int r = flat >> 5;       // 32 float4 per row
        int kq = flat & 31;
        int row = row0 + r;
        float4 v = make_float4(0.f, 0.f, 0.f, 0.f);
        if (row < N) v = *reinterpret_cast<const float4*>(&X[row * DIN + kq * 4]);
        xs[r][kq * 4 + 0] = v.x;
        xs[r][kq * 4 + 1] = v.y;
        xs[r][kq * 4 + 2] = v.z;
        xs[r][kq * 4 + 3] = v.w;
    }
    // stage W tile: 128 k x 64 cols = 2048 float4, 8 per thread
    #pragma unroll
    for (int i = 0; i < 8; ++i) {
        int flat = t + i * 256;
        int k = flat >> 4;       // 16 float4 per k-row
        int cq = flat & 15;
        float4 v = *reinterpret_cast<const float4*>(&W[k * M + col0 + cq * 4]);
        *reinterpret_cast<float4*>(&wsm[k][cq * 4]) = v;
    }
    __syncthreads();

    int tc = t & 15, tr = t >> 4;
    float acc[4][4] = {};
    #pragma unroll 4
    for (int k = 0; k < DIN; ++k) {
        float4 b = *reinterpret_cast<const float4*>(&wsm[k][tc * 4]);
        #pragma unroll
        for (int i = 0; i < 4; ++i) {
            float a = xs[tr * 4 + i][k];
            acc[i][0] += a * b.x;
            acc[i][1] += a * b.y;
            acc[i][2] += a * b.z;
            acc[i][3] += a * b.w;
        }
    }
    #pragma unroll
    for (int i = 0; i < 4; ++i) {
        int row = row0 + tr * 4 + i;
        if (row < N) {
            float4 v = make_float4(acc[i][0], acc[i][1], acc[i][2], acc[i][3]);
            *reinterpret_cast<float4*>(&Y[row * M + col0 + tc * 4]) = v;
        }
    }
}

// el[n,h] = sum_d feat[n,h,d]*al[h,d]; er likewise. One wave per node.
template <int H>
__global__ __launch_bounds__(256) void lr_kernel(const float* __restrict__ feat,
                                                 const float* __restrict__ al,
                                                 const float* __restrict__ ar,
                                                 float* __restrict__ el,
                                                 float* __restrict__ er, int N) {
    int wid = (blockIdx.x * 256 + threadIdx.x) >> 6;
    int lane = threadIdx.x & 63;
    if (wid >= N) return;
    #pragma unroll
    for (int h = 0; h < H; ++h) {
        float f = feat[(wid * H + h) * 64 + lane];
        float sl = f * al[h * 64 + lane];
        float sr = f * ar[h * 64 + lane];
        #pragma unroll
        for (int o = 32; o; o >>= 1) {
            sl += __shfl_xor(sl, o);
            sr += __shfl_xor(sr, o);
        }
        if (lane == 0) {
            el[wid * H + h] = sl;
            er[wid * H + h] = sr;
        }
    }
}

__device__ __forceinline__ float leaky(float x) { return x > 0.f ? x : 0.2f * x; }

// One wave per destination node: edge softmax (max, denom) + weighted
// aggregation over incoming edges, then bias + activation.
// FINAL=false: out[n,h*64+d] = elu(val).  FINAL=true: out[n*64+d] = mean_h relu(val).
template <int H, bool FINAL>
__global__ __launch_bounds__(256) void agg_kernel(const int* __restrict__ row_ptr,
                                                  const int* __restrict__ csr_src,
                                                  const float* __restrict__ el,
                                                  const float* __restrict__ er,
                                                  const float* __restrict__ feat,
                                                  const float* __restrict__ bias,
                                                  float* __restrict__ out, int N) {
    int wid = (blockIdx.x * 256 + threadIdx.x) >> 6;
    int lane = threadIdx.x & 63;
    if (wid >= N) return;
    int beg = row_ptr[wid];
    int deg = row_ptr[wid + 1] - beg;
    float outacc = 0.f;
    #pragma unroll
    for (int h = 0; h < H; ++h) {
        float ern = er[wid * H + h];
        // pass 1: running max of leaky(el[src]+er[dst])
        float mx = -INFINITY;
        for (int i = lane; i < deg; i += 64) {
            int s = csr_src[beg + i];
            mx = fmaxf(mx, leaky(el[s * H + h] + ern));
        }
        #pragma unroll
        for (int o = 32; o; o >>= 1) mx = fmaxf(mx, __shfl_xor(mx, o));
        // pass 2: softmax denominator
        float dn = 0.f;
        for (int i = lane; i < deg; i += 64) {
            int s = csr_src[beg + i];
            dn += __expf(leaky(el[s * H + h] + ern) - mx);
        }
        #pragma unroll
        for (int o = 32; o; o >>= 1) dn += __shfl_xor(dn, o);
        // pass 3: weighted accumulate (lane = feature dim, serial over edges)
        float acc = 0.f;
        for (int i = 0; i < deg; ++i) {
            int s = csr_src[beg + i];
            float w = __expf(leaky(el[s * H + h] + ern) - mx);
            acc += w * feat[(s * H + h) * 64 + lane];
        }
        float val = (deg > 0) ? acc / dn : 0.f;
        val += bias[h * 64 + lane];
        if (FINAL) {
            outacc += (val > 0.f ? val : 0.f);  // relu
        } else {
            out[(wid * H + h) * 64 + lane] = val > 0.f ? val : expm1f(val);  // elu
        }
    }
    if (FINAL) out[wid * 64 + lane] = outacc * (1.f / H);
}

extern "C" void kernel_launch(void* const* d_in, const int* in_sizes, int n_in,
                              void* d_out, int out_size, void* d_ws, size_t ws_size,
                              hipStream_t stream) {
    const float* feature = (const float*)d_in[0];
    const int*   src     = (const int*)d_in[1];
    const int*   dst     = (const int*)d_in[2];
    const float* W1      = (const float*)d_in[3];
    const float* al1     = (const float*)d_in[4];
    const float* ar1     = (const float*)d_in[5];
    const float* b1      = (const float*)d_in[6];
    const float* W2      = (const float*)d_in[7];
    const float* al2     = (const float*)d_in[8];
    const float* ar2     = (const float*)d_in[9];
    const float* b2      = (const float*)d_in[10];
    float* out = (float*)d_out;

    const int N = in_sizes[0] / DIN;   // 50000
    const int E = in_sizes[1];         // 800000
    const int H1 = 2, H2 = 4;

    // workspace carve-up (256B aligned)
    char* ws = (char*)d_ws;
    size_t off = 0;
    auto alloc = [&](size_t bytes) {
        char* p = ws + off;
        off += (bytes + 255) & ~size_t(255);
        return p;
    };
    int*   csr_src = (int*)alloc(sizeof(int) * E);
    int*   row_ptr = (int*)alloc(sizeof(int) * (N + 1));
    int*   deg     = (int*)alloc(sizeof(int) * N);
    int*   cursor  = (int*)alloc(sizeof(int) * N);
    float* el1     = (float*)alloc(sizeof(float) * N * H1);
    float* er1     = (float*)alloc(sizeof(float) * N * H1);
    float* el2     = (float*)alloc(sizeof(float) * N * H2);
    float* er2     = (float*)alloc(sizeof(float) * N * H2);
    float* featR   = (float*)alloc(sizeof(float) * N * 256);  // feat1 then feat2
    float* h1      = (float*)alloc(sizeof(float) * N * 128);
    (void)ws_size;

    float* feat1 = featR;  // [N,128]
    float* feat2 = featR;  // [N,256] overwrites feat1 (dead by then)

    // --- CSR build ---
    zero_i32<<<(N + 255) / 256, 256, 0, stream>>>(deg, N);
    count_deg<<<(E + 255) / 256, 256, 0, stream>>>(dst, deg, E);
    scan_kernel<<<1, 1024, 0, stream>>>(deg, row_ptr, cursor, N);
    scatter_kernel<<<(E + 255) / 256, 256, 0, stream>>>(src, dst, cursor, csr_src, E);

    // --- layer 1 ---
    {
        dim3 grid((N + 63) / 64, 128 / 64);
        gemm_f32<<<grid, 256, 0, stream>>>(feature, W1, feat1, N, 128);
    }
    lr_kernel<2><<<(N + 3) / 4, 256, 0, stream>>>(feat1, al1, ar1, el1, er1, N);
    agg_kernel<2, false><<<(N + 3) / 4, 256, 0, stream>>>(row_ptr, csr_src, el1, er1,
                                                          feat1, b1, h1, N);

    // --- layer 2 ---
    {
        dim3 grid((N + 63) / 64, 256 / 64);
        gemm_f32<<<grid, 256, 0, stream>>>(h1, W2, feat2, N, 256);
    }
    lr_kernel<4><<<(N + 3) / 4, 256, 0, stream>>>(feat2, al2, ar2, el2, er2, N);
    agg_kernel<4, true><<<(N + 3) / 4, 256, 0, stream>>>(row_ptr, csr_src, el2, er2,
                                                         feat2, b2, out, N);
}

// Round 4
// 592.935 us; speedup vs baseline: 1.5696x; 1.5696x over previous
//
#include <hip/hip_runtime.h>
#include <hip/hip_bf16.h>
#include <math.h>

// ---------------------------------------------------------------------------
// GAT 2-layer decoder. N=50000 nodes, E=800000 edges, DIN=128.
// Layer1: W1[128,128], H=2, D=64, elu. Layer2: W2[128,256], H=4, D=64, relu.
// Output: mean over 4 heads -> [N,64] f32.
// Round 3 (resubmit): head-fused aggregation — one edge sweep covers all H
// heads (lane l -> head l/G, dims (l%G)*H, G=64/H). CSR indices preloaded
// into a register + __shfl; first-64 edge scores cached in registers.
// ---------------------------------------------------------------------------

#define DIN 128

__global__ void zero_i32(int* __restrict__ p, int n) {
    int i = blockIdx.x * 256 + threadIdx.x;
    if (i < n) p[i] = 0;
}

__global__ void count_deg(const int* __restrict__ dst, int* __restrict__ deg, int E) {
    int e = blockIdx.x * 256 + threadIdx.x;
    if (e < E) atomicAdd(&deg[dst[e]], 1);
}

// Single-block scan over deg -> row_ptr (exclusive), cursor copy, row_ptr[N]=E.
__global__ __launch_bounds__(1024) void scan_kernel(const int* __restrict__ deg,
                                                    int* __restrict__ row_ptr,
                                                    int* __restrict__ cursor, int N) {
    __shared__ int sums[1024];
    int t = threadIdx.x;
    int chunk = (N + 1023) / 1024;
    int b = t * chunk;
    int e = min(b + chunk, N);
    int s = 0;
    for (int i = b; i < e; ++i) s += deg[i];
    sums[t] = s;
    __syncthreads();
    for (int o = 1; o < 1024; o <<= 1) {
        int v = (t >= o) ? sums[t - o] : 0;
        __syncthreads();
        sums[t] += v;
        __syncthreads();
    }
    int run = (t == 0) ? 0 : sums[t - 1];
    for (int i = b; i < e; ++i) {
        row_ptr[i] = run;
        cursor[i] = run;
        run += deg[i];
    }
    if (t == 0) row_ptr[N] = sums[1023];
}

__global__ void scatter_kernel(const int* __restrict__ src, const int* __restrict__ dst,
                               int* __restrict__ cursor, int* __restrict__ csr_src, int E) {
    int e = blockIdx.x * 256 + threadIdx.x;
    if (e < E) {
        int pos = atomicAdd(&cursor[dst[e]], 1);
        csr_src[pos] = src[e];
    }
}

// Y[N,M] = X[N,128] @ W[128,M].  BM=64, BN=64, BK=128(full K). 256 threads,
// each computes 4x4 outputs. grid = (ceil(N/64), M/64).
__global__ __launch_bounds__(256) void gemm_f32(const float* __restrict__ X,
                                                const float* __restrict__ W,
                                                float* __restrict__ Y, int N, int M) {
    __shared__ float xs[64][DIN + 1];
    __shared__ float wsm[DIN][64];
    int row0 = blockIdx.x * 64;
    int col0 = blockIdx.y * 64;
    int t = threadIdx.x;

    #pragma unroll
    for (int i = 0; i < 8; ++i) {
        int flat = t + i * 256;
        int r = flat >> 5;
        int kq = flat & 31;
        int row = row0 + r;
        float4 v = make_float4(0.f, 0.f, 0.f, 0.f);
        if (row < N) v = *reinterpret_cast<const float4*>(&X[row * DIN + kq * 4]);
        xs[r][kq * 4 + 0] = v.x;
        xs[r][kq * 4 + 1] = v.y;
        xs[r][kq * 4 + 2] = v.z;
        xs[r][kq * 4 + 3] = v.w;
    }
    #pragma unroll
    for (int i = 0; i < 8; ++i) {
        int flat = t + i * 256;
        int k = flat >> 4;
        int cq = flat & 15;
        float4 v = *reinterpret_cast<const float4*>(&W[k * M + col0 + cq * 4]);
        *reinterpret_cast<float4*>(&wsm[k][cq * 4]) = v;
    }
    __syncthreads();

    int tc = t & 15, tr = t >> 4;
    float acc[4][4] = {};
    #pragma unroll 4
    for (int k = 0; k < DIN; ++k) {
        float4 b = *reinterpret_cast<const float4*>(&wsm[k][tc * 4]);
        #pragma unroll
        for (int i = 0; i < 4; ++i) {
            float a = xs[tr * 4 + i][k];
            acc[i][0] += a * b.x;
            acc[i][1] += a * b.y;
            acc[i][2] += a * b.z;
            acc[i][3] += a * b.w;
        }
    }
    #pragma unroll
    for (int i = 0; i < 4; ++i) {
        int row = row0 + tr * 4 + i;
        if (row < N) {
            float4 v = make_float4(acc[i][0], acc[i][1], acc[i][2], acc[i][3]);
            *reinterpret_cast<float4*>(&Y[row * M + col0 + tc * 4]) = v;
        }
    }
}

// el[n,h] = sum_d feat[n,h,d]*al[h,d]; er likewise. One wave per node.
template <int H>
__global__ __launch_bounds__(256) void lr_kernel(const float* __restrict__ feat,
                                                 const float* __restrict__ al,
                                                 const float* __restrict__ ar,
                                                 float* __restrict__ el,
                                                 float* __restrict__ er, int N) {
    int wid = (blockIdx.x * 256 + threadIdx.x) >> 6;
    int lane = threadIdx.x & 63;
    if (wid >= N) return;
    #pragma unroll
    for (int h = 0; h < H; ++h) {
        float f = feat[(wid * H + h) * 64 + lane];
        float sl = f * al[h * 64 + lane];
        float sr = f * ar[h * 64 + lane];
        #pragma unroll
        for (int o = 32; o; o >>= 1) {
            sl += __shfl_xor(sl, o);
            sr += __shfl_xor(sr, o);
        }
        if (lane == 0) {
            el[wid * H + h] = sl;
            er[wid * H + h] = sr;
        }
    }
}

__device__ __forceinline__ float leaky(float x) { return x > 0.f ? x : 0.2f * x; }

// One wave per destination node, ALL heads in one edge sweep.
// Lane l -> head h = l/G, dim block (l%G)*H, with G = 64/H.
// feat row [H][64] = 64 lanes x H floats: lane l loads feat[s*H*64 + l*H ..].
// Score passes: lane l covers edge chunk positions (l%G) across chunks, head h.
// First 64 CSR indices preloaded in a register (shfl-broadcast); first 64
// edge scores cached in registers (ec[c]) and shfl'd in the accumulate.
// FINAL=false: out[n*H*64 + l*H ..] = elu(val). FINAL=true: out[n*64+d]=mean_h relu.
template <int H, bool FINAL>
__global__ __launch_bounds__(256) void agg_kernel(const int* __restrict__ row_ptr,
                                                  const int* __restrict__ csr_src,
                                                  const float* __restrict__ el,
                                                  const float* __restrict__ er,
                                                  const float* __restrict__ feat,
                                                  const float* __restrict__ bias,
                                                  float* __restrict__ out, int N) {
    constexpr int G = 64 / H;  // edges per score-pass iteration / lanes per head
    int wid = (blockIdx.x * 256 + threadIdx.x) >> 6;
    int lane = threadIdx.x & 63;
    if (wid >= N) return;
    int beg = row_ptr[wid];
    int deg = row_ptr[wid + 1] - beg;
    int h = lane / G;
    int gl = lane % G;

    float vals[H];
    if (deg == 0) {
        #pragma unroll
        for (int j = 0; j < H; ++j) vals[j] = bias[lane * H + j];
    } else {
        float ern = er[wid * H + h];
        int sreg = csr_src[beg + min(lane, deg - 1)];  // first 64 indices, one per lane

        // --- pass A: scores for first 64 edges (register-cached) + running max ---
        float ec[H];
        float mx = -INFINITY;
        #pragma unroll
        for (int c = 0; c < H; ++c) {
            int idx = c * G + gl;               // < 64 always (H*G == 64)
            int s = __shfl(sreg, idx);
            float e = -INFINITY;
            if (idx < deg) e = leaky(el[s * H + h] + ern);
            ec[c] = e;
            mx = fmaxf(mx, e);
        }
        for (int i0 = 64; i0 < deg; i0 += G) {  // rare tail (deg > 64)
            int idx = i0 + gl;
            if (idx < deg) {
                int s = csr_src[beg + idx];
                mx = fmaxf(mx, leaky(el[s * H + h] + ern));
            }
        }
        #pragma unroll
        for (int o = G / 2; o >= 1; o >>= 1) mx = fmaxf(mx, __shfl_xor(mx, o));

        // --- pass B: softmax denominator (from cached scores) ---
        float dn = 0.f;
        #pragma unroll
        for (int c = 0; c < H; ++c) {
            int idx = c * G + gl;
            if (idx < deg) dn += __expf(ec[c] - mx);
        }
        for (int i0 = 64; i0 < deg; i0 += G) {
            int idx = i0 + gl;
            if (idx < deg) {
                int s = csr_src[beg + idx];
                dn += __expf(leaky(el[s * H + h] + ern) - mx);
            }
        }
        #pragma unroll
        for (int o = G / 2; o >= 1; o >>= 1) dn += __shfl_xor(dn, o);

        // --- pass C: weighted accumulate, one sweep for all heads ---
        float acc[H] = {};
        #pragma unroll
        for (int c = 0; c < H; ++c) {
            int lim = deg - c * G;
            if (lim > G) lim = G;
            for (int j = 0; j < lim; ++j) {
                int s = __shfl(sreg, c * G + j);      // wave-uniform broadcast
                float e = __shfl(ec[c], h * G + j);   // score for (edge, this head)
                float w = __expf(e - mx);
                if constexpr (H == 4) {
                    float4 f = *reinterpret_cast<const float4*>(&feat[(size_t)s * 256 + lane * 4]);
                    acc[0] += w * f.x; acc[1] += w * f.y;
                    acc[2] += w * f.z; acc[3] += w * f.w;
                } else {
                    float2 f = *reinterpret_cast<const float2*>(&feat[(size_t)s * 128 + lane * 2]);
                    acc[0] += w * f.x; acc[1] += w * f.y;
                }
            }
        }
        for (int i = 64; i < deg; ++i) {              // rare tail
            int s = csr_src[beg + i];
            float w = __expf(leaky(el[s * H + h] + ern) - mx);
            if constexpr (H == 4) {
                float4 f = *reinterpret_cast<const float4*>(&feat[(size_t)s * 256 + lane * 4]);
                acc[0] += w * f.x; acc[1] += w * f.y;
                acc[2] += w * f.z; acc[3] += w * f.w;
            } else {
                float2 f = *reinterpret_cast<const float2*>(&feat[(size_t)s * 128 + lane * 2]);
                acc[0] += w * f.x; acc[1] += w * f.y;
            }
        }
        float inv = 1.0f / dn;
        #pragma unroll
        for (int j = 0; j < H; ++j) vals[j] = acc[j] * inv + bias[lane * H + j];
    }

    if (FINAL) {
        float o4[H];
        #pragma unroll
        for (int j = 0; j < H; ++j) {
            float v = vals[j] > 0.f ? vals[j] : 0.f;  // relu
            v += __shfl_xor(v, 16);                   // sum the 4 head groups
            v += __shfl_xor(v, 32);
            o4[j] = v * (1.0f / H);
        }
        if (lane < 16) {
            float4 v = make_float4(o4[0], o4[1], o4[2], o4[3]);
            *reinterpret_cast<float4*>(&out[(size_t)wid * 64 + lane * 4]) = v;
        }
    } else {
        float2 v;
        v.x = vals[0] > 0.f ? vals[0] : expm1f(vals[0]);  // elu
        v.y = vals[1] > 0.f ? vals[1] : expm1f(vals[1]);
        *reinterpret_cast<float2*>(&out[(size_t)wid * 128 + lane * 2]) = v;
    }
}

extern "C" void kernel_launch(void* const* d_in, const int* in_sizes, int n_in,
                              void* d_out, int out_size, void* d_ws, size_t ws_size,
                              hipStream_t stream) {
    const float* feature = (const float*)d_in[0];
    const int*   src     = (const int*)d_in[1];
    const int*   dst     = (const int*)d_in[2];
    const float* W1      = (const float*)d_in[3];
    const float* al1     = (const float*)d_in[4];
    const float* ar1     = (const float*)d_in[5];
    const float* b1      = (const float*)d_in[6];
    const float* W2      = (const float*)d_in[7];
    const float* al2     = (const float*)d_in[8];
    const float* ar2     = (const float*)d_in[9];
    const float* b2      = (const float*)d_in[10];
    float* out = (float*)d_out;

    const int N = in_sizes[0] / DIN;   // 50000
    const int E = in_sizes[1];         // 800000
    const int H1 = 2, H2 = 4;

    char* ws = (char*)d_ws;
    size_t off = 0;
    auto alloc = [&](size_t bytes) {
        char* p = ws + off;
        off += (bytes + 255) & ~size_t(255);
        return p;
    };
    int*   csr_src = (int*)alloc(sizeof(int) * E);
    int*   row_ptr = (int*)alloc(sizeof(int) * (N + 1));
    int*   deg     = (int*)alloc(sizeof(int) * N);
    int*   cursor  = (int*)alloc(sizeof(int) * N);
    float* el1     = (float*)alloc(sizeof(float) * N * H1);
    float* er1     = (float*)alloc(sizeof(float) * N * H1);
    float* el2     = (float*)alloc(sizeof(float) * N * H2);
    float* er2     = (float*)alloc(sizeof(float) * N * H2);
    float* featR   = (float*)alloc(sizeof(float) * N * 256);  // feat1 then feat2
    float* h1      = (float*)alloc(sizeof(float) * N * 128);
    (void)ws_size;

    float* feat1 = featR;  // [N,128]
    float* feat2 = featR;  // [N,256] overwrites feat1 (dead by then)

    // --- CSR build ---
    zero_i32<<<(N + 255) / 256, 256, 0, stream>>>(deg, N);
    count_deg<<<(E + 255) / 256, 256, 0, stream>>>(dst, deg, E);
    scan_kernel<<<1, 1024, 0, stream>>>(deg, row_ptr, cursor, N);
    scatter_kernel<<<(E + 255) / 256, 256, 0, stream>>>(src, dst, cursor, csr_src, E);

    // --- layer 1 ---
    {
        dim3 grid((N + 63) / 64, 128 / 64);
        gemm_f32<<<grid, 256, 0, stream>>>(feature, W1, feat1, N, 128);
    }
    lr_kernel<2><<<(N + 3) / 4, 256, 0, stream>>>(feat1, al1, ar1, el1, er1, N);
    agg_kernel<2, false><<<(N + 3) / 4, 256, 0, stream>>>(row_ptr, csr_src, el1, er1,
                                                          feat1, b1, h1, N);

    // --- layer 2 ---
    {
        dim3 grid((N + 63) / 64, 256 / 64);
        gemm_f32<<<grid, 256, 0, stream>>>(h1, W2, feat2, N, 256);
    }
    lr_kernel<4><<<(N + 3) / 4, 256, 0, stream>>>(feat2, al2, ar2, el2, er2, N);
    agg_kernel<4, true><<<(N + 3) / 4, 256, 0, stream>>>(row_ptr, csr_src, el2, er2,
                                                         feat2, b2, out, N);
}

// Round 5
// 542.227 us; speedup vs baseline: 1.7164x; 1.0935x over previous
//
#include <hip/hip_runtime.h>
#include <hip/hip_bf16.h>
#include <math.h>

// ---------------------------------------------------------------------------
// GAT 2-layer decoder. N=50000 nodes, E=800000 edges, DIN=128.
// Layer1: W1[128,128], H=2, D=64, elu. Layer2: W2[128,256], H=4, D=64, relu.
// Output: mean over 4 heads -> [N,64] f32.
// Round 5: bf16 gather path — GEMM epilogue emits feat in BOTH f32 (for
// el/er + next GEMM) and bf16 (for the random per-edge gather in agg).
// Halves the gather bytes/edge; all arithmetic stays f32.
// ---------------------------------------------------------------------------

#define DIN 128

typedef unsigned short ushort_t;

__device__ __forceinline__ ushort_t f2bf(float f) {
    unsigned int u = __float_as_uint(f);
    unsigned int r = (u + 0x7fffu + ((u >> 16) & 1u)) >> 16;  // RNE
    return (ushort_t)r;
}
__device__ __forceinline__ float bf2f(ushort_t b) {
    return __uint_as_float(((unsigned int)b) << 16);
}

__global__ void zero_i32(int* __restrict__ p, int n) {
    int i = blockIdx.x * 256 + threadIdx.x;
    if (i < n) p[i] = 0;
}

__global__ void count_deg(const int* __restrict__ dst, int* __restrict__ deg, int E) {
    int e = blockIdx.x * 256 + threadIdx.x;
    if (e < E) atomicAdd(&deg[dst[e]], 1);
}

// Single-block scan over deg -> row_ptr (exclusive), cursor copy, row_ptr[N]=E.
__global__ __launch_bounds__(1024) void scan_kernel(const int* __restrict__ deg,
                                                    int* __restrict__ row_ptr,
                                                    int* __restrict__ cursor, int N) {
    __shared__ int sums[1024];
    int t = threadIdx.x;
    int chunk = (N + 1023) / 1024;
    int b = t * chunk;
    int e = min(b + chunk, N);
    int s = 0;
    for (int i = b; i < e; ++i) s += deg[i];
    sums[t] = s;
    __syncthreads();
    for (int o = 1; o < 1024; o <<= 1) {
        int v = (t >= o) ? sums[t - o] : 0;
        __syncthreads();
        sums[t] += v;
        __syncthreads();
    }
    int run = (t == 0) ? 0 : sums[t - 1];
    for (int i = b; i < e; ++i) {
        row_ptr[i] = run;
        cursor[i] = run;
        run += deg[i];
    }
    if (t == 0) row_ptr[N] = sums[1023];
}

__global__ void scatter_kernel(const int* __restrict__ src, const int* __restrict__ dst,
                               int* __restrict__ cursor, int* __restrict__ csr_src, int E) {
    int e = blockIdx.x * 256 + threadIdx.x;
    if (e < E) {
        int pos = atomicAdd(&cursor[dst[e]], 1);
        csr_src[pos] = src[e];
    }
}

// Y[N,M] = X[N,128] @ W[128,M], plus bf16 copy Yb. BM=64, BN=64, BK=128.
__global__ __launch_bounds__(256) void gemm_f32(const float* __restrict__ X,
                                                const float* __restrict__ W,
                                                float* __restrict__ Y,
                                                ushort_t* __restrict__ Yb,
                                                int N, int M) {
    __shared__ float xs[64][DIN + 1];
    __shared__ float wsm[DIN][64];
    int row0 = blockIdx.x * 64;
    int col0 = blockIdx.y * 64;
    int t = threadIdx.x;

    #pragma unroll
    for (int i = 0; i < 8; ++i) {
        int flat = t + i * 256;
        int r = flat >> 5;
        int kq = flat & 31;
        int row = row0 + r;
        float4 v = make_float4(0.f, 0.f, 0.f, 0.f);
        if (row < N) v = *reinterpret_cast<const float4*>(&X[row * DIN + kq * 4]);
        xs[r][kq * 4 + 0] = v.x;
        xs[r][kq * 4 + 1] = v.y;
        xs[r][kq * 4 + 2] = v.z;
        xs[r][kq * 4 + 3] = v.w;
    }
    #pragma unroll
    for (int i = 0; i < 8; ++i) {
        int flat = t + i * 256;
        int k = flat >> 4;
        int cq = flat & 15;
        float4 v = *reinterpret_cast<const float4*>(&W[k * M + col0 + cq * 4]);
        *reinterpret_cast<float4*>(&wsm[k][cq * 4]) = v;
    }
    __syncthreads();

    int tc = t & 15, tr = t >> 4;
    float acc[4][4] = {};
    #pragma unroll 4
    for (int k = 0; k < DIN; ++k) {
        float4 b = *reinterpret_cast<const float4*>(&wsm[k][tc * 4]);
        #pragma unroll
        for (int i = 0; i < 4; ++i) {
            float a = xs[tr * 4 + i][k];
            acc[i][0] += a * b.x;
            acc[i][1] += a * b.y;
            acc[i][2] += a * b.z;
            acc[i][3] += a * b.w;
        }
    }
    #pragma unroll
    for (int i = 0; i < 4; ++i) {
        int row = row0 + tr * 4 + i;
        if (row < N) {
            float4 v = make_float4(acc[i][0], acc[i][1], acc[i][2], acc[i][3]);
            *reinterpret_cast<float4*>(&Y[row * M + col0 + tc * 4]) = v;
            ushort4 bv;
            bv.x = f2bf(acc[i][0]); bv.y = f2bf(acc[i][1]);
            bv.z = f2bf(acc[i][2]); bv.w = f2bf(acc[i][3]);
            *reinterpret_cast<ushort4*>(&Yb[(size_t)row * M + col0 + tc * 4]) = bv;
        }
    }
}

// el[n,h] = sum_d feat[n,h,d]*al[h,d]; er likewise. One wave per node.
template <int H>
__global__ __launch_bounds__(256) void lr_kernel(const float* __restrict__ feat,
                                                 const float* __restrict__ al,
                                                 const float* __restrict__ ar,
                                                 float* __restrict__ el,
                                                 float* __restrict__ er, int N) {
    int wid = (blockIdx.x * 256 + threadIdx.x) >> 6;
    int lane = threadIdx.x & 63;
    if (wid >= N) return;
    #pragma unroll
    for (int h = 0; h < H; ++h) {
        float f = feat[(wid * H + h) * 64 + lane];
        float sl = f * al[h * 64 + lane];
        float sr = f * ar[h * 64 + lane];
        #pragma unroll
        for (int o = 32; o; o >>= 1) {
            sl += __shfl_xor(sl, o);
            sr += __shfl_xor(sr, o);
        }
        if (lane == 0) {
            el[wid * H + h] = sl;
            er[wid * H + h] = sr;
        }
    }
}

__device__ __forceinline__ float leaky(float x) { return x > 0.f ? x : 0.2f * x; }

// One wave per destination node, ALL heads in one edge sweep; feat gathered
// in bf16 (halves bytes/edge), math in f32.
// Lane l -> head h = l/G, dim block (l%G)*H, with G = 64/H.
// FINAL=false: out[n*H*64 + l*H ..] = elu(val). FINAL=true: out[n*64+d]=mean_h relu.
template <int H, bool FINAL>
__global__ __launch_bounds__(256) void agg_kernel(const int* __restrict__ row_ptr,
                                                  const int* __restrict__ csr_src,
                                                  const float* __restrict__ el,
                                                  const float* __restrict__ er,
                                                  const ushort_t* __restrict__ featb,
                                                  const float* __restrict__ bias,
                                                  float* __restrict__ out, int N) {
    constexpr int G = 64 / H;  // edges per score-pass iteration / lanes per head
    int wid = (blockIdx.x * 256 + threadIdx.x) >> 6;
    int lane = threadIdx.x & 63;
    if (wid >= N) return;
    int beg = row_ptr[wid];
    int deg = row_ptr[wid + 1] - beg;
    int h = lane / G;
    int gl = lane % G;

    float vals[H];
    if (deg == 0) {
        #pragma unroll
        for (int j = 0; j < H; ++j) vals[j] = bias[lane * H + j];
    } else {
        float ern = er[wid * H + h];
        int sreg = csr_src[beg + min(lane, deg - 1)];  // first 64 indices, one per lane

        // --- pass A: scores for first 64 edges (register-cached) + running max ---
        float ec[H];
        float mx = -INFINITY;
        #pragma unroll
        for (int c = 0; c < H; ++c) {
            int idx = c * G + gl;               // < 64 always (H*G == 64)
            int s = __shfl(sreg, idx);
            float e = -INFINITY;
            if (idx < deg) e = leaky(el[s * H + h] + ern);
            ec[c] = e;
            mx = fmaxf(mx, e);
        }
        for (int i0 = 64; i0 < deg; i0 += G) {  // rare tail (deg > 64)
            int idx = i0 + gl;
            if (idx < deg) {
                int s = csr_src[beg + idx];
                mx = fmaxf(mx, leaky(el[s * H + h] + ern));
            }
        }
        #pragma unroll
        for (int o = G / 2; o >= 1; o >>= 1) mx = fmaxf(mx, __shfl_xor(mx, o));

        // --- pass B: softmax denominator (from cached scores) ---
        float dn = 0.f;
        #pragma unroll
        for (int c = 0; c < H; ++c) {
            int idx = c * G + gl;
            if (idx < deg) dn += __expf(ec[c] - mx);
        }
        for (int i0 = 64; i0 < deg; i0 += G) {
            int idx = i0 + gl;
            if (idx < deg) {
                int s = csr_src[beg + idx];
                dn += __expf(leaky(el[s * H + h] + ern) - mx);
            }
        }
        #pragma unroll
        for (int o = G / 2; o >= 1; o >>= 1) dn += __shfl_xor(dn, o);

        // --- pass C: weighted accumulate, one sweep for all heads (bf16 rows) ---
        float acc[H] = {};
        #pragma unroll
        for (int c = 0; c < H; ++c) {
            int lim = deg - c * G;
            if (lim > G) lim = G;
            for (int j = 0; j < lim; ++j) {
                int s = __shfl(sreg, c * G + j);      // wave-uniform broadcast
                float e = __shfl(ec[c], h * G + j);   // score for (edge, this head)
                float w = __expf(e - mx);
                if constexpr (H == 4) {
                    ushort4 f = *reinterpret_cast<const ushort4*>(&featb[(size_t)s * 256 + lane * 4]);
                    acc[0] += w * bf2f(f.x); acc[1] += w * bf2f(f.y);
                    acc[2] += w * bf2f(f.z); acc[3] += w * bf2f(f.w);
                } else {
                    ushort2 f = *reinterpret_cast<const ushort2*>(&featb[(size_t)s * 128 + lane * 2]);
                    acc[0] += w * bf2f(f.x); acc[1] += w * bf2f(f.y);
                }
            }
        }
        for (int i = 64; i < deg; ++i) {              // rare tail
            int s = csr_src[beg + i];
            float w = __expf(leaky(el[s * H + h] + ern) - mx);
            if constexpr (H == 4) {
                ushort4 f = *reinterpret_cast<const ushort4*>(&featb[(size_t)s * 256 + lane * 4]);
                acc[0] += w * bf2f(f.x); acc[1] += w * bf2f(f.y);
                acc[2] += w * bf2f(f.z); acc[3] += w * bf2f(f.w);
            } else {
                ushort2 f = *reinterpret_cast<const ushort2*>(&featb[(size_t)s * 128 + lane * 2]);
                acc[0] += w * bf2f(f.x); acc[1] += w * bf2f(f.y);
            }
        }
        float inv = 1.0f / dn;
        #pragma unroll
        for (int j = 0; j < H; ++j) vals[j] = acc[j] * inv + bias[lane * H + j];
    }

    if (FINAL) {
        float o4[H];
        #pragma unroll
        for (int j = 0; j < H; ++j) {
            float v = vals[j] > 0.f ? vals[j] : 0.f;  // relu
            v += __shfl_xor(v, 16);                   // sum the 4 head groups
            v += __shfl_xor(v, 32);
            o4[j] = v * (1.0f / H);
        }
        if (lane < 16) {
            float4 v = make_float4(o4[0], o4[1], o4[2], o4[3]);
            *reinterpret_cast<float4*>(&out[(size_t)wid * 64 + lane * 4]) = v;
        }
    } else {
        float2 v;
        v.x = vals[0] > 0.f ? vals[0] : expm1f(vals[0]);  // elu
        v.y = vals[1] > 0.f ? vals[1] : expm1f(vals[1]);
        *reinterpret_cast<float2*>(&out[(size_t)wid * 128 + lane * 2]) = v;
    }
}

extern "C" void kernel_launch(void* const* d_in, const int* in_sizes, int n_in,
                              void* d_out, int out_size, void* d_ws, size_t ws_size,
                              hipStream_t stream) {
    const float* feature = (const float*)d_in[0];
    const int*   src     = (const int*)d_in[1];
    const int*   dst     = (const int*)d_in[2];
    const float* W1      = (const float*)d_in[3];
    const float* al1     = (const float*)d_in[4];
    const float* ar1     = (const float*)d_in[5];
    const float* b1      = (const float*)d_in[6];
    const float* W2      = (const float*)d_in[7];
    const float* al2     = (const float*)d_in[8];
    const float* ar2     = (const float*)d_in[9];
    const float* b2      = (const float*)d_in[10];
    float* out = (float*)d_out;

    const int N = in_sizes[0] / DIN;   // 50000
    const int E = in_sizes[1];         // 800000
    const int H1 = 2, H2 = 4;

    char* ws = (char*)d_ws;
    size_t off = 0;
    auto alloc = [&](size_t bytes) {
        char* p = ws + off;
        off += (bytes + 255) & ~size_t(255);
        return p;
    };
    int*      csr_src = (int*)alloc(sizeof(int) * E);
    int*      row_ptr = (int*)alloc(sizeof(int) * (N + 1));
    int*      deg     = (int*)alloc(sizeof(int) * N);
    int*      cursor  = (int*)alloc(sizeof(int) * N);
    float*    el1     = (float*)alloc(sizeof(float) * N * H1);
    float*    er1     = (float*)alloc(sizeof(float) * N * H1);
    float*    el2     = (float*)alloc(sizeof(float) * N * H2);
    float*    er2     = (float*)alloc(sizeof(float) * N * H2);
    float*    featR   = (float*)alloc(sizeof(float) * N * 256);   // feat1 then feat2 (f32)
    ushort_t* featB   = (ushort_t*)alloc(sizeof(ushort_t) * N * 256); // bf16 copy
    float*    h1      = (float*)alloc(sizeof(float) * N * 128);
    (void)ws_size;

    float*    feat1  = featR;   // [N,128] f32
    float*    feat2  = featR;   // [N,256] f32 (overwrites feat1, dead by then)
    ushort_t* feat1b = featB;   // [N,128] bf16
    ushort_t* feat2b = featB;   // [N,256] bf16

    // --- CSR build ---
    zero_i32<<<(N + 255) / 256, 256, 0, stream>>>(deg, N);
    count_deg<<<(E + 255) / 256, 256, 0, stream>>>(dst, deg, E);
    scan_kernel<<<1, 1024, 0, stream>>>(deg, row_ptr, cursor, N);
    scatter_kernel<<<(E + 255) / 256, 256, 0, stream>>>(src, dst, cursor, csr_src, E);

    // --- layer 1 ---
    {
        dim3 grid((N + 63) / 64, 128 / 64);
        gemm_f32<<<grid, 256, 0, stream>>>(feature, W1, feat1, feat1b, N, 128);
    }
    lr_kernel<2><<<(N + 3) / 4, 256, 0, stream>>>(feat1, al1, ar1, el1, er1, N);
    agg_kernel<2, false><<<(N + 3) / 4, 256, 0, stream>>>(row_ptr, csr_src, el1, er1,
                                                          feat1b, b1, h1, N);

    // --- layer 2 ---
    {
        dim3 grid((N + 63) / 64, 256 / 64);
        gemm_f32<<<grid, 256, 0, stream>>>(h1, W2, feat2, feat2b, N, 256);
    }
    lr_kernel<4><<<(N + 3) / 4, 256, 0, stream>>>(feat2, al2, ar2, el2, er2, N);
    agg_kernel<4, true><<<(N + 3) / 4, 256, 0, stream>>>(row_ptr, csr_src, el2, er2,
                                                         feat2b, b2, out, N);
}

// Round 17
// 405.455 us; speedup vs baseline: 2.2954x; 1.3373x over previous
//
#include <hip/hip_runtime.h>
#include <hip/hip_bf16.h>
#include <math.h>

// ---------------------------------------------------------------------------
// GAT 2-layer decoder. N=50000 nodes, E=800000 edges, DIN=128.
// Layer1: W1[128,128], H=2, D=64, elu. Layer2: W2[128,256], H=4, D=64, relu.
// Output: mean over 4 heads -> [N,64] f32.
// Round 6 (resubmit x11): (1) hierarchical 3-phase CSR scan (was 110us
// single-block); (2) el/er fused into GEMM epilogue (col-block == head),
// f32 feat dropped — GEMM writes bf16 feat only; lr_kernel deleted.
// ---------------------------------------------------------------------------

#define DIN 128

typedef unsigned short ushort_t;

__device__ __forceinline__ ushort_t f2bf(float f) {
    unsigned int u = __float_as_uint(f);
    unsigned int r = (u + 0x7fffu + ((u >> 16) & 1u)) >> 16;  // RNE
    return (ushort_t)r;
}
__device__ __forceinline__ float bf2f(ushort_t b) {
    return __uint_as_float(((unsigned int)b) << 16);
}

__global__ void zero_i32(int* __restrict__ p, int n) {
    int i = blockIdx.x * 256 + threadIdx.x;
    if (i < n) p[i] = 0;
}

__global__ void count_deg(const int* __restrict__ dst, int* __restrict__ deg, int E) {
    int e = blockIdx.x * 256 + threadIdx.x;
    if (e < E) atomicAdd(&deg[dst[e]], 1);
}

// --- hierarchical exclusive scan of deg[N] -> row_ptr/cursor ---------------
// NOTE: scan_p2 is single-block => requires NB <= 256, i.e. N <= 65536.
__global__ __launch_bounds__(256) void scan_p1(const int* __restrict__ deg,
                                               int* __restrict__ bsum, int N) {
    int i = blockIdx.x * 256 + threadIdx.x;
    int v = (i < N) ? deg[i] : 0;
    #pragma unroll
    for (int o = 32; o; o >>= 1) v += __shfl_xor(v, o);
    __shared__ int w4[4];
    if ((threadIdx.x & 63) == 0) w4[threadIdx.x >> 6] = v;
    __syncthreads();
    if (threadIdx.x == 0) bsum[blockIdx.x] = w4[0] + w4[1] + w4[2] + w4[3];
}

__global__ __launch_bounds__(256) void scan_p2(int* __restrict__ bsum, int NB) {
    __shared__ int s[256];
    int t = threadIdx.x;
    s[t] = (t < NB) ? bsum[t] : 0;
    __syncthreads();
    for (int o = 1; o < 256; o <<= 1) {
        int u = (t >= o) ? s[t - o] : 0;
        __syncthreads();
        s[t] += u;
        __syncthreads();
    }
    if (t < NB) bsum[t] = (t == 0) ? 0 : s[t - 1];  // exclusive
}

__global__ __launch_bounds__(256) void scan_p3(const int* __restrict__ deg,
                                               const int* __restrict__ bsum,
                                               int* __restrict__ row_ptr,
                                               int* __restrict__ cursor, int N, int E) {
    __shared__ int s[256];
    int t = threadIdx.x;
    int i = blockIdx.x * 256 + t;
    s[t] = (i < N) ? deg[i] : 0;
    __syncthreads();
    for (int o = 1; o < 256; o <<= 1) {
        int u = (t >= o) ? s[t - o] : 0;
        __syncthreads();
        s[t] += u;
        __syncthreads();
    }
    int ex = ((t == 0) ? 0 : s[t - 1]) + bsum[blockIdx.x];
    if (i < N) {
        row_ptr[i] = ex;
        cursor[i] = ex;
    }
    if (i == 0) row_ptr[N] = E;
}

__global__ void scatter_kernel(const int* __restrict__ src, const int* __restrict__ dst,
                               int* __restrict__ cursor, int* __restrict__ csr_src, int E) {
    int e = blockIdx.x * 256 + threadIdx.x;
    if (e < E) {
        int pos = atomicAdd(&cursor[dst[e]], 1);
        csr_src[pos] = src[e];
    }
}

// Yb[N,M](bf16) = X[N,128] @ W[128,M]; fused el/er epilogue.
// BM=64, BN=64(==D, so blockIdx.y == head), BK=128. 256 thr, 4x4 acc each.
__global__ __launch_bounds__(256) void gemm_fused(const float* __restrict__ X,
                                                  const float* __restrict__ W,
                                                  ushort_t* __restrict__ Yb,
                                                  const float* __restrict__ al,
                                                  const float* __restrict__ ar,
                                                  float* __restrict__ el,
                                                  float* __restrict__ er,
                                                  int N, int M, int H) {
    __shared__ float xs[64][DIN + 1];
    __shared__ float wsm[DIN][64];
    int row0 = blockIdx.x * 64;
    int hh = blockIdx.y;           // head index (col block of 64 == one head)
    int col0 = hh * 64;
    int t = threadIdx.x;

    #pragma unroll
    for (int i = 0; i < 8; ++i) {
        int flat = t + i * 256;
        int r = flat >> 5;
        int kq = flat & 31;
        int row = row0 + r;
        float4 v = make_float4(0.f, 0.f, 0.f, 0.f);
        if (row < N) v = *reinterpret_cast<const float4*>(&X[row * DIN + kq * 4]);
        xs[r][kq * 4 + 0] = v.x;
        xs[r][kq * 4 + 1] = v.y;
        xs[r][kq * 4 + 2] = v.z;
        xs[r][kq * 4 + 3] = v.w;
    }
    #pragma unroll
    for (int i = 0; i < 8; ++i) {
        int flat = t + i * 256;
        int k = flat >> 4;
        int cq = flat & 15;
        float4 v = *reinterpret_cast<const float4*>(&W[k * M + col0 + cq * 4]);
        *reinterpret_cast<float4*>(&wsm[k][cq * 4]) = v;
    }
    __syncthreads();

    int tc = t & 15, tr = t >> 4;
    float acc[4][4] = {};
    #pragma unroll 4
    for (int k = 0; k < DIN; ++k) {
        float4 b = *reinterpret_cast<const float4*>(&wsm[k][tc * 4]);
        #pragma unroll
        for (int i = 0; i < 4; ++i) {
            float a = xs[tr * 4 + i][k];
            acc[i][0] += a * b.x;
            acc[i][1] += a * b.y;
            acc[i][2] += a * b.z;
            acc[i][3] += a * b.w;
        }
    }

    // epilogue: bf16 store + fused el/er (reduce over tc's 16 lanes)
    float4 a4 = *reinterpret_cast<const float4*>(&al[hh * 64 + tc * 4]);
    float4 r4 = *reinterpret_cast<const float4*>(&ar[hh * 64 + tc * 4]);
    #pragma unroll
    for (int i = 0; i < 4; ++i) {
        int row = row0 + tr * 4 + i;
        float pel = acc[i][0] * a4.x + acc[i][1] * a4.y + acc[i][2] * a4.z + acc[i][3] * a4.w;
        float per = acc[i][0] * r4.x + acc[i][1] * r4.y + acc[i][2] * r4.z + acc[i][3] * r4.w;
        #pragma unroll
        for (int o = 1; o < 16; o <<= 1) {
            pel += __shfl_xor(pel, o);
            per += __shfl_xor(per, o);
        }
        if (row < N) {
            ushort4 bv;
            bv.x = f2bf(acc[i][0]); bv.y = f2bf(acc[i][1]);
            bv.z = f2bf(acc[i][2]); bv.w = f2bf(acc[i][3]);
            *reinterpret_cast<ushort4*>(&Yb[(size_t)row * M + col0 + tc * 4]) = bv;
            if (tc == 0) {
                el[row * H + hh] = pel;
                er[row * H + hh] = per;
            }
        }
    }
}

__device__ __forceinline__ float leaky(float x) { return x > 0.f ? x : 0.2f * x; }

// One wave per destination node, ALL heads in one edge sweep; feat gathered
// in bf16, math in f32. Lane l -> head h = l/G, dim block (l%G)*H, G = 64/H.
// FINAL=false: out[n*H*64 + l*H ..] = elu(val). FINAL=true: out[n*64+d]=mean_h relu.
template <int H, bool FINAL>
__global__ __launch_bounds__(256) void agg_kernel(const int* __restrict__ row_ptr,
                                                  const int* __restrict__ csr_src,
                                                  const float* __restrict__ el,
                                                  const float* __restrict__ er,
                                                  const ushort_t* __restrict__ featb,
                                                  const float* __restrict__ bias,
                                                  float* __restrict__ out, int N) {
    constexpr int G = 64 / H;
    int wid = (blockIdx.x * 256 + threadIdx.x) >> 6;
    int lane = threadIdx.x & 63;
    if (wid >= N) return;
    int beg = row_ptr[wid];
    int deg = row_ptr[wid + 1] - beg;
    int h = lane / G;
    int gl = lane % G;

    float vals[H];
    if (deg == 0) {
        #pragma unroll
        for (int j = 0; j < H; ++j) vals[j] = bias[lane * H + j];
    } else {
        float ern = er[wid * H + h];
        int sreg = csr_src[beg + min(lane, deg - 1)];

        // pass A: scores for first 64 edges (register-cached) + running max
        float ec[H];
        float mx = -INFINITY;
        #pragma unroll
        for (int c = 0; c < H; ++c) {
            int idx = c * G + gl;
            int s = __shfl(sreg, idx);
            float e = -INFINITY;
            if (idx < deg) e = leaky(el[s * H + h] + ern);
            ec[c] = e;
            mx = fmaxf(mx, e);
        }
        for (int i0 = 64; i0 < deg; i0 += G) {
            int idx = i0 + gl;
            if (idx < deg) {
                int s = csr_src[beg + idx];
                mx = fmaxf(mx, leaky(el[s * H + h] + ern));
            }
        }
        #pragma unroll
        for (int o = G / 2; o >= 1; o >>= 1) mx = fmaxf(mx, __shfl_xor(mx, o));

        // pass B: softmax denominator
        float dn = 0.f;
        #pragma unroll
        for (int c = 0; c < H; ++c) {
            int idx = c * G + gl;
            if (idx < deg) dn += __expf(ec[c] - mx);
        }
        for (int i0 = 64; i0 < deg; i0 += G) {
            int idx = i0 + gl;
            if (idx < deg) {
                int s = csr_src[beg + idx];
                dn += __expf(leaky(el[s * H + h] + ern) - mx);
            }
        }
        #pragma unroll
        for (int o = G / 2; o >= 1; o >>= 1) dn += __shfl_xor(dn, o);

        // pass C: weighted accumulate (bf16 rows)
        float acc[H] = {};
        #pragma unroll
        for (int c = 0; c < H; ++c) {
            int lim = deg - c * G;
            if (lim > G) lim = G;
            for (int j = 0; j < lim; ++j) {
                int s = __shfl(sreg, c * G + j);
                float e = __shfl(ec[c], h * G + j);
                float w = __expf(e - mx);
                if constexpr (H == 4) {
                    ushort4 f = *reinterpret_cast<const ushort4*>(&featb[(size_t)s * 256 + lane * 4]);
                    acc[0] += w * bf2f(f.x); acc[1] += w * bf2f(f.y);
                    acc[2] += w * bf2f(f.z); acc[3] += w * bf2f(f.w);
                } else {
                    ushort2 f = *reinterpret_cast<const ushort2*>(&featb[(size_t)s * 128 + lane * 2]);
                    acc[0] += w * bf2f(f.x); acc[1] += w * bf2f(f.y);
                }
            }
        }
        for (int i = 64; i < deg; ++i) {
            int s = csr_src[beg + i];
            float w = __expf(leaky(el[s * H + h] + ern) - mx);
            if constexpr (H == 4) {
                ushort4 f = *reinterpret_cast<const ushort4*>(&featb[(size_t)s * 256 + lane * 4]);
                acc[0] += w * bf2f(f.x); acc[1] += w * bf2f(f.y);
                acc[2] += w * bf2f(f.z); acc[3] += w * bf2f(f.w);
            } else {
                ushort2 f = *reinterpret_cast<const ushort2*>(&featb[(size_t)s * 128 + lane * 2]);
                acc[0] += w * bf2f(f.x); acc[1] += w * bf2f(f.y);
            }
        }
        float inv = 1.0f / dn;
        #pragma unroll
        for (int j = 0; j < H; ++j) vals[j] = acc[j] * inv + bias[lane * H + j];
    }

    if (FINAL) {
        float o4[H];
        #pragma unroll
        for (int j = 0; j < H; ++j) {
            float v = vals[j] > 0.f ? vals[j] : 0.f;  // relu
            v += __shfl_xor(v, 16);
            v += __shfl_xor(v, 32);
            o4[j] = v * (1.0f / H);
        }
        if (lane < 16) {
            float4 v = make_float4(o4[0], o4[1], o4[2], o4[3]);
            *reinterpret_cast<float4*>(&out[(size_t)wid * 64 + lane * 4]) = v;
        }
    } else {
        float2 v;
        v.x = vals[0] > 0.f ? vals[0] : expm1f(vals[0]);  // elu
        v.y = vals[1] > 0.f ? vals[1] : expm1f(vals[1]);
        *reinterpret_cast<float2*>(&out[(size_t)wid * 128 + lane * 2]) = v;
    }
}

extern "C" void kernel_launch(void* const* d_in, const int* in_sizes, int n_in,
                              void* d_out, int out_size, void* d_ws, size_t ws_size,
                              hipStream_t stream) {
    const float* feature = (const float*)d_in[0];
    const int*   src     = (const int*)d_in[1];
    const int*   dst     = (const int*)d_in[2];
    const float* W1      = (const float*)d_in[3];
    const float* al1     = (const float*)d_in[4];
    const float* ar1     = (const float*)d_in[5];
    const float* b1      = (const float*)d_in[6];
    const float* W2      = (const float*)d_in[7];
    const float* al2     = (const float*)d_in[8];
    const float* ar2     = (const float*)d_in[9];
    const float* b2      = (const float*)d_in[10];
    float* out = (float*)d_out;

    const int N = in_sizes[0] / DIN;   // 50000
    const int E = in_sizes[1];         // 800000
    const int H1 = 2, H2 = 4;
    const int NB = (N + 255) / 256;    // 196

    char* ws = (char*)d_ws;
    size_t off = 0;
    auto alloc = [&](size_t bytes) {
        char* p = ws + off;
        off += (bytes + 255) & ~size_t(255);
        return p;
    };
    int*      csr_src = (int*)alloc(sizeof(int) * E);
    int*      row_ptr = (int*)alloc(sizeof(int) * (N + 1));
    int*      deg     = (int*)alloc(sizeof(int) * N);
    int*      cursor  = (int*)alloc(sizeof(int) * N);
    int*      bsum    = (int*)alloc(sizeof(int) * NB);
    float*    el1     = (float*)alloc(sizeof(float) * N * H1);
    float*    er1     = (float*)alloc(sizeof(float) * N * H1);
    float*    el2     = (float*)alloc(sizeof(float) * N * H2);
    float*    er2     = (float*)alloc(sizeof(float) * N * H2);
    ushort_t* featB   = (ushort_t*)alloc(sizeof(ushort_t) * N * 256); // bf16 feat
    float*    h1      = (float*)alloc(sizeof(float) * N * 128);
    (void)ws_size;

    ushort_t* feat1b = featB;   // [N,128] bf16
    ushort_t* feat2b = featB;   // [N,256] bf16 (overwrites feat1b, dead by then)

    // --- CSR build ---
    zero_i32<<<(N + 255) / 256, 256, 0, stream>>>(deg, N);
    count_deg<<<(E + 255) / 256, 256, 0, stream>>>(dst, deg, E);
    scan_p1<<<NB, 256, 0, stream>>>(deg, bsum, N);
    scan_p2<<<1, 256, 0, stream>>>(bsum, NB);
    scan_p3<<<NB, 256, 0, stream>>>(deg, bsum, row_ptr, cursor, N, E);
    scatter_kernel<<<(E + 255) / 256, 256, 0, stream>>>(src, dst, cursor, csr_src, E);

    // --- layer 1 ---
    {
        dim3 grid((N + 63) / 64, H1);
        gemm_fused<<<grid, 256, 0, stream>>>(feature, W1, feat1b, al1, ar1, el1, er1,
                                             N, H1 * 64, H1);
    }
    agg_kernel<2, false><<<(N + 3) / 4, 256, 0, stream>>>(row_ptr, csr_src, el1, er1,
                                                          feat1b, b1, h1, N);

    // --- layer 2 ---
    {
        dim3 grid((N + 63) / 64, H2);
        gemm_fused<<<grid, 256, 0, stream>>>(h1, W2, feat2b, al2, ar2, el2, er2,
                                             N, H2 * 64, H2);
    }
    agg_kernel<4, true><<<(N + 3) / 4, 256, 0, stream>>>(row_ptr, csr_src, el2, er2,
                                                         feat2b, b2, out, N);
}